// Round 1
// baseline (238.698 us; speedup 1.0000x reference)
//
#include <hip/hip_runtime.h>
#include <math.h>

#define BDIM 16
#define LDIM 512
#define CDIM 1024
#define NH 8
#define HD 128
#define MROWS (BDIM * LDIM)   /* 8192 */
#define N3 (3 * CDIM)         /* 3072 */

typedef unsigned short u16;
typedef unsigned long long u64;
typedef short s8v __attribute__((ext_vector_type(8)));   // 8 bf16 = 4 VGPRs (MFMA A/B frag)
typedef short s4v __attribute__((ext_vector_type(4)));   // 4 bf16 = 2 VGPRs
typedef float f32x4 __attribute__((ext_vector_type(4))); // MFMA C/D frag

__device__ __forceinline__ float sigmoidf_(float z) {
    return 1.0f / (1.0f + __expf(-z));
}
__device__ __forceinline__ u16 f2bf(float f) {
    union { float f; unsigned int u; } v; v.f = f;
    unsigned int u = v.u;
    unsigned int r = (u + 0x7FFFu + ((u >> 16) & 1u)) >> 16;   // round-nearest-even
    return (u16)r;
}
__device__ __forceinline__ float bf2f(u16 b) {
    union { unsigned int u; float f; } v; v.u = ((unsigned int)b) << 16;
    return v.f;
}

// ---------------- Kernel 1: degree = adj.sum(-1)  +  adj bitmask pack ----------------
__global__ void degree_kernel(const float* __restrict__ adj, float* __restrict__ deg,
                              u64* __restrict__ adjbits) {
    int row = blockIdx.x;            // 0..B*L-1
    int lane = threadIdx.x;          // 0..63
    const float* a = adj + (size_t)row * LDIM;
    float s = 0.f;
    #pragma unroll
    for (int mc = 0; mc < LDIM; mc += 64) {
        float v = a[mc + lane];
        s += v;
        u64 m = __ballot(v != 0.f);
        if (lane == 0) adjbits[(size_t)row * (LDIM / 64) + (mc >> 6)] = m;
    }
    #pragma unroll
    for (int off = 32; off > 0; off >>= 1) s += __shfl_down(s, off);
    if (lane == 0) deg[row] = s;
}

// ---------------- Kernel 2: xg = bf16( x * sigmoid(deg*W_d + b_d) ) ----------------
__global__ void gate_kernel(const float* __restrict__ x, const float* __restrict__ deg,
                            const float* __restrict__ Wd, const float* __restrict__ bd,
                            u16* __restrict__ xg) {
    int row = blockIdx.x;
    int t = threadIdx.x;
    float d = deg[row];
    float4 xv = ((const float4*)(x + (size_t)row * CDIM))[t];
    float4 wv = ((const float4*)Wd)[t];
    float4 bv = ((const float4*)bd)[t];
    s4v o;
    o.x = (short)f2bf(xv.x * sigmoidf_(d * wv.x + bv.x));
    o.y = (short)f2bf(xv.y * sigmoidf_(d * wv.y + bv.y));
    o.z = (short)f2bf(xv.z * sigmoidf_(d * wv.z + bv.z));
    o.w = (short)f2bf(xv.w * sigmoidf_(d * wv.w + bv.w));
    ((s4v*)(xg + (size_t)row * CDIM))[t] = o;
}

// ---------------- Kernel 3: Wt[n][k] = bf16(W[k][n]) (transpose 1024x3072) -----------
__global__ void packW_kernel(const float* __restrict__ W, u16* __restrict__ Wt) {
    __shared__ float tile[64][65];
    int k0 = blockIdx.x * 64, n0 = blockIdx.y * 64;
    int tx = threadIdx.x & 63, ty = threadIdx.x >> 6;  // ty 0..3
    #pragma unroll
    for (int yy = ty; yy < 64; yy += 4)
        tile[yy][tx] = W[(size_t)(k0 + yy) * N3 + n0 + tx];
    __syncthreads();
    #pragma unroll
    for (int yy = ty; yy < 64; yy += 4)
        Wt[(size_t)(n0 + yy) * CDIM + k0 + tx] = f2bf(tile[tx][yy]);
}

// ---------------- Kernel 4: 256x256 8-phase bf16 MFMA GEMM (T2+T3+T4+T5) ------------
// qkv = xg @ W + b : M=8192, N=3072, K=1024. A=[M][K] bf16, Bt=[N][K] bf16.
// 512 thr = 8 waves (2M x 4N), per-wave 128x64 out, acc[8][4]. BK=64, LDS 128KB dbuf.
// Swizzle: 16B slots, slot = row*8 + (seg ^ (row&7)); applied on the GLOBAL address,
// LDS dest linear (global_load_lds constraint). ds_read_b128 frags: 2 lanes/bank, free.
// Schedule (per iter = 2 K-tiles c0=2i [buf0], c1=2i+1 [buf1]); chunk = 64 rows:
//   P1 rd A-lo,B-lo(c0) | stage c1:A1,A3     P5 rd A-lo,B-lo(c1) | stage c0+2:A1,A3
//   P2 rd B-hi(c0)      | stage c0+2:A0,A2   P6 rd B-hi(c1)      | stage c0+3:A0,A2
//   P3 rd A-hi(c0)      | stage c0+2:B0,B1   P7 rd A-hi(c1)      | stage c0+3:B0,B1
//   P4 (regs cached)    | stage c0+2:B2,B3   P8                  | stage c0+3:B2,B3
// Counted s_waitcnt vmcnt(6) ONLY at P4/P8 (2 loads/phase x 3 phases in flight);
// raw s_barrier (asm, memory clobber) so prefetch loads stay in flight across it.
// Every staged chunk targets a region whose last ds_read was >=1 barrier-pair earlier.
// Fused chunk epilogue: 0 -> sigmoid ksig [B,H,L,HD]; 1 -> resb; 2 -> vt [B,H,HD,L].
__global__ __launch_bounds__(512, 2) void gemm_bf16_kernel(const u16* __restrict__ A,
                                                           const u16* __restrict__ Bt,
                                                           const float* __restrict__ bias,
                                                           u16* __restrict__ ksig,
                                                           u16* __restrict__ resb,
                                                           u16* __restrict__ vt) {
    __shared__ __align__(16) u16 As[2][256 * 64];
    __shared__ __align__(16) u16 Bs[2][256 * 64];
    int t = threadIdx.x;
    int lane = t & 63, w = t >> 6;
    int i15 = lane & 15, quad = lane >> 4;
    int wm = w >> 2, wn = w & 3;
    int m0 = blockIdx.y * 256, n0 = blockIdx.x * 256;

    int srow = lane >> 3;        // staging: row-in-8 per lane
    int sseg = lane & 7;         // staging: seg slot per lane

    f32x4 acc[8][4];
    #pragma unroll
    for (int i = 0; i < 8; ++i)
        #pragma unroll
        for (int j = 0; j < 4; ++j) acc[i][j] = (f32x4)(0.f);

    auto stA = [&](int kt, int R) {   // stage A rows [R, R+64) of K-tile kt
        int row = R + w * 8 + srow;
        int seg = sseg ^ (row & 7);
        const u16* g = A + (size_t)(m0 + row) * CDIM + kt * 64 + seg * 8;
        __builtin_amdgcn_global_load_lds(
            (const __attribute__((address_space(1))) unsigned int*)g,
            (__attribute__((address_space(3))) unsigned int*)&As[kt & 1][(R + w * 8) * 64], 16, 0, 0);
    };
    auto stB = [&](int kt, int R) {
        int row = R + w * 8 + srow;
        int seg = sseg ^ (row & 7);
        const u16* g = Bt + (size_t)(n0 + row) * CDIM + kt * 64 + seg * 8;
        __builtin_amdgcn_global_load_lds(
            (const __attribute__((address_space(1))) unsigned int*)g,
            (__attribute__((address_space(3))) unsigned int*)&Bs[kt & 1][(R + w * 8) * 64], 16, 0, 0);
    };
    auto rdA = [&](int d, int mf, int kc) -> s8v {
        int row = wm * 128 + mf * 16 + i15;
        int slot = row * 8 + ((kc * 4 + quad) ^ (row & 7));
        return *(const s8v*)&As[d][slot * 8];
    };
    auto rdB = [&](int d, int nf, int kc) -> s8v {
        int row = wn * 64 + nf * 16 + i15;
        int slot = row * 8 + ((kc * 4 + quad) ^ (row & 7));
        return *(const s8v*)&Bs[d][slot * 8];
    };

#define BAR() asm volatile("s_barrier" ::: "memory")
#define VMW(n) asm volatile("s_waitcnt vmcnt(" #n ")" ::: "memory")
#define MFMA_ __builtin_amdgcn_mfma_f32_16x16x32_bf16

    // ---- prologue: tile0 fully; tile1 all but A1,A3 (those staged at iter0-P1) ----
    stA(0, 0); stA(0, 64); stA(0, 128); stA(0, 192);
    stB(0, 0); stB(0, 64); stB(0, 128); stB(0, 192);
    stA(1, 0); stA(1, 128);
    stB(1, 0); stB(1, 64); stB(1, 128); stB(1, 192);
    VMW(6);                          // tile0's 8 loads retired (FIFO), tile1's 6 in flight
    BAR();

    for (int it = 0; it < 8; ++it) {
        int c1 = 2 * it + 1;         // odd tile, buf1
        int cn = 2 * it + 2;         // next even tile, buf0
        int cm = 2 * it + 3;         // next odd tile, buf1
        bool st = (it < 7);
        s8v a0[4][2], a1[4][2], b0[2][2], b1[2][2];

        // ================= tile c0 (buf0) =================
        // ---- P1: (qm0,qn0) ----
        #pragma unroll
        for (int mf = 0; mf < 4; ++mf)
            #pragma unroll
            for (int kc = 0; kc < 2; ++kc) a0[mf][kc] = rdA(0, mf, kc);
        #pragma unroll
        for (int nf = 0; nf < 2; ++nf)
            #pragma unroll
            for (int kc = 0; kc < 2; ++kc) b0[nf][kc] = rdB(0, nf, kc);
        stA(c1, 64); stA(c1, 192);
        BAR();
        __builtin_amdgcn_s_setprio(1);
        #pragma unroll
        for (int mf = 0; mf < 4; ++mf)
            #pragma unroll
            for (int nf = 0; nf < 2; ++nf)
                #pragma unroll
                for (int kc = 0; kc < 2; ++kc)
                    acc[mf][nf] = MFMA_(a0[mf][kc], b0[nf][kc], acc[mf][nf], 0, 0, 0);
        __builtin_amdgcn_s_setprio(0);
        BAR();

        // ---- P2: (qm0,qn1) ----
        #pragma unroll
        for (int nf = 0; nf < 2; ++nf)
            #pragma unroll
            for (int kc = 0; kc < 2; ++kc) b1[nf][kc] = rdB(0, 2 + nf, kc);
        if (st) { stA(cn, 0); stA(cn, 128); }
        BAR();
        __builtin_amdgcn_s_setprio(1);
        #pragma unroll
        for (int mf = 0; mf < 4; ++mf)
            #pragma unroll
            for (int nf = 0; nf < 2; ++nf)
                #pragma unroll
                for (int kc = 0; kc < 2; ++kc)
                    acc[mf][2 + nf] = MFMA_(a0[mf][kc], b1[nf][kc], acc[mf][2 + nf], 0, 0, 0);
        __builtin_amdgcn_s_setprio(0);
        BAR();

        // ---- P3: (qm1,qn0) ----
        #pragma unroll
        for (int mf = 0; mf < 4; ++mf)
            #pragma unroll
            for (int kc = 0; kc < 2; ++kc) a1[mf][kc] = rdA(0, 4 + mf, kc);
        if (st) { stB(cn, 0); stB(cn, 64); }
        BAR();
        __builtin_amdgcn_s_setprio(1);
        #pragma unroll
        for (int mf = 0; mf < 4; ++mf)
            #pragma unroll
            for (int nf = 0; nf < 2; ++nf)
                #pragma unroll
                for (int kc = 0; kc < 2; ++kc)
                    acc[4 + mf][nf] = MFMA_(a1[mf][kc], b0[nf][kc], acc[4 + mf][nf], 0, 0, 0);
        __builtin_amdgcn_s_setprio(0);
        BAR();

        // ---- P4: (qm1,qn1), checkpoint ----
        if (st) { stB(cn, 128); stB(cn, 192); }
        BAR();
        __builtin_amdgcn_s_setprio(1);
        #pragma unroll
        for (int mf = 0; mf < 4; ++mf)
            #pragma unroll
            for (int nf = 0; nf < 2; ++nf)
                #pragma unroll
                for (int kc = 0; kc < 2; ++kc)
                    acc[4 + mf][2 + nf] = MFMA_(a1[mf][kc], b1[nf][kc], acc[4 + mf][2 + nf], 0, 0, 0);
        __builtin_amdgcn_s_setprio(0);
        if (st) { VMW(6); } else { VMW(0); }   // tile c1 fully landed
        BAR();

        // ================= tile c1 (buf1) =================
        // ---- P5: (qm0,qn0) ----
        #pragma unroll
        for (int mf = 0; mf < 4; ++mf)
            #pragma unroll
            for (int kc = 0; kc < 2; ++kc) a0[mf][kc] = rdA(1, mf, kc);
        #pragma unroll
        for (int nf = 0; nf < 2; ++nf)
            #pragma unroll
            for (int kc = 0; kc < 2; ++kc) b0[nf][kc] = rdB(1, nf, kc);
        if (st) { stA(cn, 64); stA(cn, 192); }
        BAR();
        __builtin_amdgcn_s_setprio(1);
        #pragma unroll
        for (int mf = 0; mf < 4; ++mf)
            #pragma unroll
            for (int nf = 0; nf < 2; ++nf)
                #pragma unroll
                for (int kc = 0; kc < 2; ++kc)
                    acc[mf][nf] = MFMA_(a0[mf][kc], b0[nf][kc], acc[mf][nf], 0, 0, 0);
        __builtin_amdgcn_s_setprio(0);
        BAR();

        // ---- P6: (qm0,qn1) ----
        #pragma unroll
        for (int nf = 0; nf < 2; ++nf)
            #pragma unroll
            for (int kc = 0; kc < 2; ++kc) b1[nf][kc] = rdB(1, 2 + nf, kc);
        if (st) { stA(cm, 0); stA(cm, 128); }
        BAR();
        __builtin_amdgcn_s_setprio(1);
        #pragma unroll
        for (int mf = 0; mf < 4; ++mf)
            #pragma unroll
            for (int nf = 0; nf < 2; ++nf)
                #pragma unroll
                for (int kc = 0; kc < 2; ++kc)
                    acc[mf][2 + nf] = MFMA_(a0[mf][kc], b1[nf][kc], acc[mf][2 + nf], 0, 0, 0);
        __builtin_amdgcn_s_setprio(0);
        BAR();

        // ---- P7: (qm1,qn0) ----
        #pragma unroll
        for (int mf = 0; mf < 4; ++mf)
            #pragma unroll
            for (int kc = 0; kc < 2; ++kc) a1[mf][kc] = rdA(1, 4 + mf, kc);
        if (st) { stB(cm, 0); stB(cm, 64); }
        BAR();
        __builtin_amdgcn_s_setprio(1);
        #pragma unroll
        for (int mf = 0; mf < 4; ++mf)
            #pragma unroll
            for (int nf = 0; nf < 2; ++nf)
                #pragma unroll
                for (int kc = 0; kc < 2; ++kc)
                    acc[4 + mf][nf] = MFMA_(a1[mf][kc], b0[nf][kc], acc[4 + mf][nf], 0, 0, 0);
        __builtin_amdgcn_s_setprio(0);
        BAR();

        // ---- P8: (qm1,qn1), checkpoint ----
        if (st) { stB(cm, 128); stB(cm, 192); }
        BAR();
        __builtin_amdgcn_s_setprio(1);
        #pragma unroll
        for (int mf = 0; mf < 4; ++mf)
            #pragma unroll
            for (int nf = 0; nf < 2; ++nf)
                #pragma unroll
                for (int kc = 0; kc < 2; ++kc)
                    acc[4 + mf][2 + nf] = MFMA_(a1[mf][kc], b1[nf][kc], acc[4 + mf][2 + nf], 0, 0, 0);
        __builtin_amdgcn_s_setprio(0);
        if (st) { VMW(6); }                    // tile cn (next buf0) fully landed
        BAR();
    }

    // ---- fused epilogue ----
    int chunk = n0 >> 10;
    #pragma unroll
    for (int nf = 0; nf < 4; ++nf) {
        int ncol = n0 + wn * 64 + nf * 16 + i15;
        float bv = bias[ncol];
        #pragma unroll
        for (int mf = 0; mf < 8; ++mf) {
            int mbase = m0 + wm * 128 + mf * 16 + quad * 4;
            if (chunk == 0) {
                int h = (ncol >> 7) & 7, d = ncol & 127;
                #pragma unroll
                for (int r = 0; r < 4; ++r) {
                    int mrow = mbase + r;
                    int bb = mrow >> 9, l = mrow & 511;
                    ksig[(((size_t)bb * NH + h) * LDIM + l) * HD + d] = f2bf(sigmoidf_(acc[mf][nf][r] + bv));
                }
            } else if (chunk == 1) {
                #pragma unroll
                for (int r = 0; r < 4; ++r) {
                    int mrow = mbase + r;
                    resb[(size_t)mrow * CDIM + (ncol - CDIM)] = f2bf(acc[mf][nf][r] + bv);
                }
            } else {
                int h = (ncol >> 7) & 7, d = ncol & 127;
                int bb = mbase >> 9, l = mbase & 511;   // 4 consecutive l, no 512-wrap
                s4v pk;
                pk.x = (short)f2bf(acc[mf][nf][0] + bv);
                pk.y = (short)f2bf(acc[mf][nf][1] + bv);
                pk.z = (short)f2bf(acc[mf][nf][2] + bv);
                pk.w = (short)f2bf(acc[mf][nf][3] + bv);
                *(s4v*)&vt[(((size_t)bb * NH + h) * HD + d) * LDIM + l] = pk;
            }
        }
    }
#undef BAR
#undef VMW
#undef MFMA_
}

// ---------------- Kernel 5: fused MFMA attention ----------------
// 1D grid id = l*128 + b*8 + h  ->  id%8 == h: all l-blocks of (b,h) share an XCD
// (K/Vt head slices stay L2-resident). Per block: 64 l-rows, 4 waves x 16 rows.
// K/Vt staged via global_load_lds with XOR swizzle; adj applied from bitmask words.
// O_unnorm += P.V, rowsum += sum(P); divide once at the end (linear norm).
__global__ __launch_bounds__(256) void attn_kernel(const u16* __restrict__ ksig,
                                                   const u16* __restrict__ vt,
                                                   const u16* __restrict__ resb,
                                                   const u64* __restrict__ adjbits,
                                                   float* __restrict__ out) {
    __shared__ __align__(16) u16 lds_ks[64 * 128];  // swizzled: slot = row*16 + (seg^(row&15))
    __shared__ __align__(16) u16 lds_vt[128 * 64];  // swizzled: slot = row*8 + (seg^(row&7))
    __shared__ __align__(16) u16 lds_ps[4][16][72]; // per-wave P tile [l][m], 64 + 8 pad

    int t = threadIdx.x;
    int lane = t & 63, w = t >> 6;
    int i15 = lane & 15, quad = lane >> 4;
    int bid = blockIdx.x;
    int l0 = (bid >> 7) * 64;
    int b  = (bid >> 3) & 15;
    int h  = bid & 7;

    const u16* ksig_bh = ksig + ((size_t)b * NH + h) * LDIM * HD;
    const u16* vt_bh   = vt + ((size_t)b * NH + h) * HD * LDIM;
    const u64* abits   = adjbits + ((size_t)b * LDIM + l0 + w * 16 + quad * 4) * (LDIM / 64);

    // Q A-frags from global (sigmoid pre-applied in GEMM epilogue)
    s8v aQ[4];
    {
        const u16* qrow = ksig_bh + (size_t)(l0 + w * 16 + i15) * HD + quad * 8;
        #pragma unroll
        for (int kc = 0; kc < 4; ++kc) aQ[kc] = *(const s8v*)(qrow + kc * 32);
    }

    f32x4 accO[8];
    #pragma unroll
    for (int i = 0; i < 8; ++i) accO[i] = (f32x4)(0.f);
    float prs[4] = {0.f, 0.f, 0.f, 0.f};

    const float scale = 0.08838834764831845f;  // 1/sqrt(128)

    for (int m0 = 0; m0 < LDIM; m0 += 64) {
        // --- stage K tile via DMA: 64 rows x 16 segs, 4 insts/thread ---
        #pragma unroll
        for (int p = 0; p < 4; ++p) {
            int sb = (w * 4 + p) * 64;
            int s = sb + lane;
            int row = s >> 4;
            int seg = (s & 15) ^ (row & 15);
            const u16* g = ksig_bh + (size_t)(m0 + row) * HD + seg * 8;
            __builtin_amdgcn_global_load_lds(
                (const __attribute__((address_space(1))) unsigned int*)g,
                (__attribute__((address_space(3))) unsigned int*)&lds_ks[sb * 8], 16, 0, 0);
        }
        // --- stage V^T tile via DMA: 128 rows x 8 segs, 4 insts/thread ---
        #pragma unroll
        for (int p = 0; p < 4; ++p) {
            int sb = (w * 4 + p) * 64;
            int s = sb + lane;
            int row = s >> 3;
            int seg = (s & 7) ^ (row & 7);
            const u16* g = vt_bh + (size_t)row * LDIM + m0 + seg * 8;
            __builtin_amdgcn_global_load_lds(
                (const __attribute__((address_space(1))) unsigned int*)g,
                (__attribute__((address_space(3))) unsigned int*)&lds_vt[sb * 8], 16, 0, 0);
        }
        // --- adj mask words for this m-chunk (broadcast loads, hide under DMA) ---
        unsigned int mw0[4], mw1[4];
        #pragma unroll
        for (int r = 0; r < 4; ++r) {
            u64 wrd = abits[(size_t)r * (LDIM / 64) + (m0 >> 6)];
            mw0[r] = (unsigned int)wrd;
            mw1[r] = (unsigned int)(wrd >> 32);
        }
        __syncthreads();

        // --- S = sig(Q) sig(K)^T : 4 key-tiles x 4 k-steps ---
        f32x4 S[4];
        #pragma unroll
        for (int nt = 0; nt < 4; ++nt) {
            S[nt] = (f32x4)(0.f);
            #pragma unroll
            for (int kc = 0; kc < 4; ++kc) {
                int row = nt * 16 + i15;
                int slot = row * 16 + ((kc * 4 + quad) ^ (row & 15));
                s8v bK = *(const s8v*)&lds_ks[slot * 8];
                S[nt] = __builtin_amdgcn_mfma_f32_16x16x32_bf16(aQ[kc], bK, S[nt], 0, 0, 0);
            }
        }

        // --- mask via bit-test, rowsum, P -> LDS (per-wave, no barrier) ---
        #pragma unroll
        for (int nt = 0; nt < 4; ++nt) {
            int sh = (nt & 1) * 16 + i15;
            #pragma unroll
            for (int r = 0; r < 4; ++r) {
                unsigned int half = (nt < 2) ? mw0[r] : mw1[r];
                float p = ((half >> sh) & 1u) ? S[nt][r] * scale : 0.f;
                prs[r] += p;
                lds_ps[w][quad * 4 + r][nt * 16 + i15] = f2bf(p);
            }
        }

        // --- O += P . V ---
        {
            s8v aP[2];
            #pragma unroll
            for (int ks = 0; ks < 2; ++ks)
                aP[ks] = *(const s8v*)&lds_ps[w][i15][ks * 32 + quad * 8];
            #pragma unroll
            for (int ntd = 0; ntd < 8; ++ntd) {
                #pragma unroll
                for (int ks = 0; ks < 2; ++ks) {
                    int row = ntd * 16 + i15;
                    int slot = row * 8 + ((ks * 4 + quad) ^ (row & 7));
                    s8v bV = *(const s8v*)&lds_vt[slot * 8];
                    accO[ntd] = __builtin_amdgcn_mfma_f32_16x16x32_bf16(aP[ks], bV, accO[ntd], 0, 0, 0);
                }
            }
        }
        __syncthreads();
    }

    // --- epilogue: reduce rowsums across the 16 key-lanes, normalize, +res, relu ---
    float inv[4];
    #pragma unroll
    for (int r = 0; r < 4; ++r) {
        float s = prs[r];
        s += __shfl_xor(s, 1);
        s += __shfl_xor(s, 2);
        s += __shfl_xor(s, 4);
        s += __shfl_xor(s, 8);
        inv[r] = 1.0f / (s + 1e-6f);
    }
    #pragma unroll
    for (int ntd = 0; ntd < 8; ++ntd) {
        int dcol = h * HD + ntd * 16 + i15;
        #pragma unroll
        for (int r = 0; r < 4; ++r) {
            size_t idx = ((size_t)b * LDIM + l0 + w * 16 + quad * 4 + r) * CDIM + dcol;
            float v = accO[ntd][r] * inv[r] + bf2f(resb[idx]);
            out[idx] = fmaxf(v, 0.f);
        }
    }
}

// ---------------- launch ----------------
extern "C" void kernel_launch(void* const* d_in, const int* in_sizes, int n_in,
                              void* d_out, int out_size, void* d_ws, size_t ws_size,
                              hipStream_t stream) {
    (void)in_sizes; (void)n_in; (void)out_size; (void)ws_size;
    const float* x     = (const float*)d_in[0];
    const float* adj   = (const float*)d_in[1];
    const float* W_qkv = (const float*)d_in[2];
    const float* b_qkv = (const float*)d_in[3];
    const float* W_d   = (const float*)d_in[4];
    const float* b_d   = (const float*)d_in[5];
    float* out = (float*)d_out;

    char* ws = (char*)d_ws;
    size_t off = 0;
    float* deg  = (float*)(ws + off); off += 32768;                       // 8192 f32
    u64* adjb   = (u64*)(ws + off);   off += (size_t)MROWS * 8 * 8;       // 512 KB
    u16*   xg   = (u16*)(ws + off);   off += (size_t)MROWS * CDIM * 2;    // 16 MB
    u16*   Wt   = (u16*)(ws + off);   off += (size_t)N3 * CDIM * 2;       // 6 MB
    u16*   ksig = (u16*)(ws + off);   off += (size_t)MROWS * CDIM * 2;    // 16 MB
    u16*   resb = (u16*)(ws + off);   off += (size_t)MROWS * CDIM * 2;    // 16 MB
    u16*   vt   = (u16*)(ws + off);   off += (size_t)MROWS * CDIM * 2;    // 16 MB

    degree_kernel<<<MROWS, 64, 0, stream>>>(adj, deg, adjb);
    gate_kernel<<<MROWS, 256, 0, stream>>>(x, deg, W_d, b_d, xg);
    packW_kernel<<<dim3(CDIM / 64, N3 / 64), 256, 0, stream>>>(W_qkv, Wt);
    gemm_bf16_kernel<<<dim3(N3 / 256, MROWS / 256), 512, 0, stream>>>(xg, Wt, b_qkv, ksig, resb, vt);
    attn_kernel<<<LDIM / 64 * NH * BDIM, 256, 0, stream>>>(ksig, vt, resb, adjb, out);
}

// Round 2
// 238.184 us; speedup vs baseline: 1.0022x; 1.0022x over previous
//
#include <hip/hip_runtime.h>
#include <math.h>

#define BDIM 16
#define LDIM 512
#define CDIM 1024
#define NH 8
#define HD 128
#define MROWS (BDIM * LDIM)   /* 8192 */
#define N3 (3 * CDIM)         /* 3072 */

typedef unsigned short u16;
typedef unsigned long long u64;
typedef short s8v __attribute__((ext_vector_type(8)));   // 8 bf16 = 4 VGPRs (MFMA A/B frag)
typedef short s4v __attribute__((ext_vector_type(4)));   // 4 bf16 = 2 VGPRs
typedef float f32x4 __attribute__((ext_vector_type(4))); // MFMA C/D frag

__device__ __forceinline__ float sigmoidf_(float z) {
    return 1.0f / (1.0f + __expf(-z));
}
__device__ __forceinline__ u16 f2bf(float f) {
    union { float f; unsigned int u; } v; v.f = f;
    unsigned int u = v.u;
    unsigned int r = (u + 0x7FFFu + ((u >> 16) & 1u)) >> 16;   // round-nearest-even
    return (u16)r;
}
__device__ __forceinline__ float bf2f(u16 b) {
    union { unsigned int u; float f; } v; v.u = ((unsigned int)b) << 16;
    return v.f;
}

// ---------------- Kernel 1: degree = adj.sum(-1)  +  adj bitmask pack ----------------
__global__ void degree_kernel(const float* __restrict__ adj, float* __restrict__ deg,
                              u64* __restrict__ adjbits) {
    int row = blockIdx.x;            // 0..B*L-1
    int lane = threadIdx.x;          // 0..63
    const float* a = adj + (size_t)row * LDIM;
    float s = 0.f;
    #pragma unroll
    for (int mc = 0; mc < LDIM; mc += 64) {
        float v = a[mc + lane];
        s += v;
        u64 m = __ballot(v != 0.f);
        if (lane == 0) adjbits[(size_t)row * (LDIM / 64) + (mc >> 6)] = m;
    }
    #pragma unroll
    for (int off = 32; off > 0; off >>= 1) s += __shfl_down(s, off);
    if (lane == 0) deg[row] = s;
}

// ---------------- Kernel 2: xg = bf16( x * sigmoid(deg*W_d + b_d) ) ----------------
__global__ void gate_kernel(const float* __restrict__ x, const float* __restrict__ deg,
                            const float* __restrict__ Wd, const float* __restrict__ bd,
                            u16* __restrict__ xg) {
    int row = blockIdx.x;
    int t = threadIdx.x;
    float d = deg[row];
    float4 xv = ((const float4*)(x + (size_t)row * CDIM))[t];
    float4 wv = ((const float4*)Wd)[t];
    float4 bv = ((const float4*)bd)[t];
    s4v o;
    o.x = (short)f2bf(xv.x * sigmoidf_(d * wv.x + bv.x));
    o.y = (short)f2bf(xv.y * sigmoidf_(d * wv.y + bv.y));
    o.z = (short)f2bf(xv.z * sigmoidf_(d * wv.z + bv.z));
    o.w = (short)f2bf(xv.w * sigmoidf_(d * wv.w + bv.w));
    ((s4v*)(xg + (size_t)row * CDIM))[t] = o;
}

// ---------------- Kernel 3: Wt[n][k] = bf16(W[k][n]) (transpose 1024x3072) -----------
__global__ void packW_kernel(const float* __restrict__ W, u16* __restrict__ Wt) {
    __shared__ float tile[64][65];
    int k0 = blockIdx.x * 64, n0 = blockIdx.y * 64;
    int tx = threadIdx.x & 63, ty = threadIdx.x >> 6;  // ty 0..3
    #pragma unroll
    for (int yy = ty; yy < 64; yy += 4)
        tile[yy][tx] = W[(size_t)(k0 + yy) * N3 + n0 + tx];
    __syncthreads();
    #pragma unroll
    for (int yy = ty; yy < 64; yy += 4)
        Wt[(size_t)(n0 + yy) * CDIM + k0 + tx] = f2bf(tile[tx][yy]);
}

// ---------------- Kernel 4: 256x256 8-phase bf16 MFMA GEMM (T2+T3+T4+T5) ------------
// qkv = xg @ W + b : M=8192, N=3072, K=1024. A=[M][K] bf16, Bt=[N][K] bf16.
// 512 thr = 8 waves (2M x 4N), per-wave 128x64 out, acc[8][4]. BK=64, LDS 128KB dbuf.
// Swizzle: 16B slots, slot = row*8 + (seg ^ (row&7)); applied on the GLOBAL address,
// LDS dest linear (global_load_lds constraint). ds_read_b128 frags: 2 lanes/bank, free.
//
// ROUND-1 LESSON: barriers MUST be __builtin_amdgcn_s_barrier() and vmcnt waits MUST
// be clobber-free asm. An asm("s_barrier":::"memory") makes hipcc's waitcnt pass
// assume the asm can read LDS written by in-flight global_load_lds -> it emits
// s_waitcnt vmcnt(0) before EVERY barrier, draining the pipeline each phase
// (measured: ~1200cy/phase = HBM latency, MfmaUtil 20%). Counted vmcnt only works
// with the builtin barrier (m201/m218).
//
// Schedule (per iter = 2 K-tiles c0=2i [buf0], c1=2i+1 [buf1]); chunk = 64 rows:
//   P1 rd A-lo,B-lo(c0) | stage c1:A1,A3     P5 rd A-lo,B-lo(c1) | stage c0+2:A1,A3
//   P2 rd B-hi(c0)      | stage c0+2:A0,A2   P6 rd B-hi(c1)      | stage c0+3:A0,A2
//   P3 rd A-hi(c0)      | stage c0+2:B0,B1   P7 rd A-hi(c1)      | stage c0+3:B0,B1
//   P4 (regs cached)    | stage c0+2:B2,B3   P8                  | stage c0+3:B2,B3
// vmcnt(6) ONLY at P4/P8 (wave-local FIFO: drains exactly the 8 loads of the tile
// consumed next; 6 of the following tile stay in flight). Liveness ledger: every
// stage targets a region whose last ds_read completed >=1 barrier-pair earlier.
__global__ __launch_bounds__(512, 2) void gemm_bf16_kernel(const u16* __restrict__ A,
                                                           const u16* __restrict__ Bt,
                                                           const float* __restrict__ bias,
                                                           u16* __restrict__ ksig,
                                                           u16* __restrict__ resb,
                                                           u16* __restrict__ vt) {
    __shared__ __align__(16) u16 As[2][256 * 64];
    __shared__ __align__(16) u16 Bs[2][256 * 64];
    int t = threadIdx.x;
    int lane = t & 63, w = t >> 6;
    int i15 = lane & 15, quad = lane >> 4;
    int wm = w >> 2, wn = w & 3;
    int m0 = blockIdx.y * 256, n0 = blockIdx.x * 256;

    int srow = lane >> 3;        // staging: row-in-8 per lane
    int sseg = lane & 7;         // staging: seg slot per lane

    f32x4 acc[8][4];
    #pragma unroll
    for (int i = 0; i < 8; ++i)
        #pragma unroll
        for (int j = 0; j < 4; ++j) acc[i][j] = (f32x4)(0.f);

    auto stA = [&](int kt, int R) {   // stage A rows [R, R+64) of K-tile kt
        int row = R + w * 8 + srow;
        int seg = sseg ^ (row & 7);
        const u16* g = A + (size_t)(m0 + row) * CDIM + kt * 64 + seg * 8;
        __builtin_amdgcn_global_load_lds(
            (const __attribute__((address_space(1))) unsigned int*)g,
            (__attribute__((address_space(3))) unsigned int*)&As[kt & 1][(R + w * 8) * 64], 16, 0, 0);
    };
    auto stB = [&](int kt, int R) {
        int row = R + w * 8 + srow;
        int seg = sseg ^ (row & 7);
        const u16* g = Bt + (size_t)(n0 + row) * CDIM + kt * 64 + seg * 8;
        __builtin_amdgcn_global_load_lds(
            (const __attribute__((address_space(1))) unsigned int*)g,
            (__attribute__((address_space(3))) unsigned int*)&Bs[kt & 1][(R + w * 8) * 64], 16, 0, 0);
    };
    auto rdA = [&](int d, int mf, int kc) -> s8v {
        int row = wm * 128 + mf * 16 + i15;
        int slot = row * 8 + ((kc * 4 + quad) ^ (row & 7));
        return *(const s8v*)&As[d][slot * 8];
    };
    auto rdB = [&](int d, int nf, int kc) -> s8v {
        int row = wn * 64 + nf * 16 + i15;
        int slot = row * 8 + ((kc * 4 + quad) ^ (row & 7));
        return *(const s8v*)&Bs[d][slot * 8];
    };

// builtin barrier: does NOT drain vmcnt (the whole point of counted prefetch)
#define BAR() __builtin_amdgcn_s_barrier()
// clobber-free counted wait, pinned so no stage (VMEM) can sink below it
#define VMW(n) do { __builtin_amdgcn_sched_barrier(0); \
                    asm volatile("s_waitcnt vmcnt(" #n ")"); } while (0)
#define MFMA_ __builtin_amdgcn_mfma_f32_16x16x32_bf16

    // ---- prologue: tile0 fully; tile1 all but A1,A3 (those staged at iter0-P1) ----
    stA(0, 0); stA(0, 64); stA(0, 128); stA(0, 192);
    stB(0, 0); stB(0, 64); stB(0, 128); stB(0, 192);
    stA(1, 0); stA(1, 128);
    stB(1, 0); stB(1, 64); stB(1, 128); stB(1, 192);
    VMW(6);                          // tile0's 8 loads retired (FIFO), tile1's 6 in flight
    BAR();

    for (int it = 0; it < 8; ++it) {
        int c1 = 2 * it + 1;         // odd tile, buf1
        int cn = 2 * it + 2;         // next even tile, buf0
        int cm = 2 * it + 3;         // next odd tile, buf1
        bool st = (it < 7);
        s8v a0[4][2], a1[4][2], b0[2][2], b1[2][2];

        // ================= tile c0 (buf0) =================
        // ---- P1: (qm0,qn0) ----
        #pragma unroll
        for (int mf = 0; mf < 4; ++mf)
            #pragma unroll
            for (int kc = 0; kc < 2; ++kc) a0[mf][kc] = rdA(0, mf, kc);
        #pragma unroll
        for (int nf = 0; nf < 2; ++nf)
            #pragma unroll
            for (int kc = 0; kc < 2; ++kc) b0[nf][kc] = rdB(0, nf, kc);
        stA(c1, 64); stA(c1, 192);
        BAR();
        __builtin_amdgcn_s_setprio(1);
        #pragma unroll
        for (int mf = 0; mf < 4; ++mf)
            #pragma unroll
            for (int nf = 0; nf < 2; ++nf)
                #pragma unroll
                for (int kc = 0; kc < 2; ++kc)
                    acc[mf][nf] = MFMA_(a0[mf][kc], b0[nf][kc], acc[mf][nf], 0, 0, 0);
        __builtin_amdgcn_s_setprio(0);
        BAR();

        // ---- P2: (qm0,qn1) ----
        #pragma unroll
        for (int nf = 0; nf < 2; ++nf)
            #pragma unroll
            for (int kc = 0; kc < 2; ++kc) b1[nf][kc] = rdB(0, 2 + nf, kc);
        if (st) { stA(cn, 0); stA(cn, 128); }
        BAR();
        __builtin_amdgcn_s_setprio(1);
        #pragma unroll
        for (int mf = 0; mf < 4; ++mf)
            #pragma unroll
            for (int nf = 0; nf < 2; ++nf)
                #pragma unroll
                for (int kc = 0; kc < 2; ++kc)
                    acc[mf][2 + nf] = MFMA_(a0[mf][kc], b1[nf][kc], acc[mf][2 + nf], 0, 0, 0);
        __builtin_amdgcn_s_setprio(0);
        BAR();

        // ---- P3: (qm1,qn0) ----
        #pragma unroll
        for (int mf = 0; mf < 4; ++mf)
            #pragma unroll
            for (int kc = 0; kc < 2; ++kc) a1[mf][kc] = rdA(0, 4 + mf, kc);
        if (st) { stB(cn, 0); stB(cn, 64); }
        BAR();
        __builtin_amdgcn_s_setprio(1);
        #pragma unroll
        for (int mf = 0; mf < 4; ++mf)
            #pragma unroll
            for (int nf = 0; nf < 2; ++nf)
                #pragma unroll
                for (int kc = 0; kc < 2; ++kc)
                    acc[4 + mf][nf] = MFMA_(a1[mf][kc], b0[nf][kc], acc[4 + mf][nf], 0, 0, 0);
        __builtin_amdgcn_s_setprio(0);
        BAR();

        // ---- P4: (qm1,qn1), checkpoint ----
        if (st) { stB(cn, 128); stB(cn, 192); }
        BAR();
        __builtin_amdgcn_s_setprio(1);
        #pragma unroll
        for (int mf = 0; mf < 4; ++mf)
            #pragma unroll
            for (int nf = 0; nf < 2; ++nf)
                #pragma unroll
                for (int kc = 0; kc < 2; ++kc)
                    acc[4 + mf][2 + nf] = MFMA_(a1[mf][kc], b1[nf][kc], acc[4 + mf][2 + nf], 0, 0, 0);
        __builtin_amdgcn_s_setprio(0);
        if (st) { VMW(6); } else { VMW(0); }   // tile c1 fully landed
        BAR();

        // ================= tile c1 (buf1) =================
        // ---- P5: (qm0,qn0) ----
        #pragma unroll
        for (int mf = 0; mf < 4; ++mf)
            #pragma unroll
            for (int kc = 0; kc < 2; ++kc) a0[mf][kc] = rdA(1, mf, kc);
        #pragma unroll
        for (int nf = 0; nf < 2; ++nf)
            #pragma unroll
            for (int kc = 0; kc < 2; ++kc) b0[nf][kc] = rdB(1, nf, kc);
        if (st) { stA(cn, 64); stA(cn, 192); }
        BAR();
        __builtin_amdgcn_s_setprio(1);
        #pragma unroll
        for (int mf = 0; mf < 4; ++mf)
            #pragma unroll
            for (int nf = 0; nf < 2; ++nf)
                #pragma unroll
                for (int kc = 0; kc < 2; ++kc)
                    acc[mf][nf] = MFMA_(a0[mf][kc], b0[nf][kc], acc[mf][nf], 0, 0, 0);
        __builtin_amdgcn_s_setprio(0);
        BAR();

        // ---- P6: (qm0,qn1) ----
        #pragma unroll
        for (int nf = 0; nf < 2; ++nf)
            #pragma unroll
            for (int kc = 0; kc < 2; ++kc) b1[nf][kc] = rdB(1, 2 + nf, kc);
        if (st) { stA(cm, 0); stA(cm, 128); }
        BAR();
        __builtin_amdgcn_s_setprio(1);
        #pragma unroll
        for (int mf = 0; mf < 4; ++mf)
            #pragma unroll
            for (int nf = 0; nf < 2; ++nf)
                #pragma unroll
                for (int kc = 0; kc < 2; ++kc)
                    acc[mf][2 + nf] = MFMA_(a0[mf][kc], b1[nf][kc], acc[mf][2 + nf], 0, 0, 0);
        __builtin_amdgcn_s_setprio(0);
        BAR();

        // ---- P7: (qm1,qn0) ----
        #pragma unroll
        for (int mf = 0; mf < 4; ++mf)
            #pragma unroll
            for (int kc = 0; kc < 2; ++kc) a1[mf][kc] = rdA(1, 4 + mf, kc);
        if (st) { stB(cm, 0); stB(cm, 64); }
        BAR();
        __builtin_amdgcn_s_setprio(1);
        #pragma unroll
        for (int mf = 0; mf < 4; ++mf)
            #pragma unroll
            for (int nf = 0; nf < 2; ++nf)
                #pragma unroll
                for (int kc = 0; kc < 2; ++kc)
                    acc[4 + mf][nf] = MFMA_(a1[mf][kc], b0[nf][kc], acc[4 + mf][nf], 0, 0, 0);
        __builtin_amdgcn_s_setprio(0);
        BAR();

        // ---- P8: (qm1,qn1), checkpoint ----
        if (st) { stB(cm, 128); stB(cm, 192); }
        BAR();
        __builtin_amdgcn_s_setprio(1);
        #pragma unroll
        for (int mf = 0; mf < 4; ++mf)
            #pragma unroll
            for (int nf = 0; nf < 2; ++nf)
                #pragma unroll
                for (int kc = 0; kc < 2; ++kc)
                    acc[4 + mf][2 + nf] = MFMA_(a1[mf][kc], b1[nf][kc], acc[4 + mf][2 + nf], 0, 0, 0);
        __builtin_amdgcn_s_setprio(0);
        if (st) { VMW(6); }                    // tile cn (next buf0) fully landed
        BAR();
    }

    // ---- fused epilogue ----
    int chunk = n0 >> 10;
    #pragma unroll
    for (int nf = 0; nf < 4; ++nf) {
        int ncol = n0 + wn * 64 + nf * 16 + i15;
        float bv = bias[ncol];
        #pragma unroll
        for (int mf = 0; mf < 8; ++mf) {
            int mbase = m0 + wm * 128 + mf * 16 + quad * 4;
            if (chunk == 0) {
                int h = (ncol >> 7) & 7, d = ncol & 127;
                #pragma unroll
                for (int r = 0; r < 4; ++r) {
                    int mrow = mbase + r;
                    int bb = mrow >> 9, l = mrow & 511;
                    ksig[(((size_t)bb * NH + h) * LDIM + l) * HD + d] = f2bf(sigmoidf_(acc[mf][nf][r] + bv));
                }
            } else if (chunk == 1) {
                #pragma unroll
                for (int r = 0; r < 4; ++r) {
                    int mrow = mbase + r;
                    resb[(size_t)mrow * CDIM + (ncol - CDIM)] = f2bf(acc[mf][nf][r] + bv);
                }
            } else {
                int h = (ncol >> 7) & 7, d = ncol & 127;
                int bb = mbase >> 9, l = mbase & 511;   // 4 consecutive l, no 512-wrap
                s4v pk;
                pk.x = (short)f2bf(acc[mf][nf][0] + bv);
                pk.y = (short)f2bf(acc[mf][nf][1] + bv);
                pk.z = (short)f2bf(acc[mf][nf][2] + bv);
                pk.w = (short)f2bf(acc[mf][nf][3] + bv);
                *(s4v*)&vt[(((size_t)bb * NH + h) * HD + d) * LDIM + l] = pk;
            }
        }
    }
#undef BAR
#undef VMW
#undef MFMA_
}

// ---------------- Kernel 5: fused MFMA attention ----------------
// 1D grid id = l*128 + b*8 + h  ->  id%8 == h: all l-blocks of (b,h) share an XCD
// (K/Vt head slices stay L2-resident). Per block: 64 l-rows, 4 waves x 16 rows.
// K/Vt staged via global_load_lds with XOR swizzle; adj applied from bitmask words.
// O_unnorm += P.V, rowsum += sum(P); divide once at the end (linear norm).
__global__ __launch_bounds__(256) void attn_kernel(const u16* __restrict__ ksig,
                                                   const u16* __restrict__ vt,
                                                   const u16* __restrict__ resb,
                                                   const u64* __restrict__ adjbits,
                                                   float* __restrict__ out) {
    __shared__ __align__(16) u16 lds_ks[64 * 128];  // swizzled: slot = row*16 + (seg^(row&15))
    __shared__ __align__(16) u16 lds_vt[128 * 64];  // swizzled: slot = row*8 + (seg^(row&7))
    __shared__ __align__(16) u16 lds_ps[4][16][72]; // per-wave P tile [l][m], 64 + 8 pad

    int t = threadIdx.x;
    int lane = t & 63, w = t >> 6;
    int i15 = lane & 15, quad = lane >> 4;
    int bid = blockIdx.x;
    int l0 = (bid >> 7) * 64;
    int b  = (bid >> 3) & 15;
    int h  = bid & 7;

    const u16* ksig_bh = ksig + ((size_t)b * NH + h) * LDIM * HD;
    const u16* vt_bh   = vt + ((size_t)b * NH + h) * HD * LDIM;
    const u64* abits   = adjbits + ((size_t)b * LDIM + l0 + w * 16 + quad * 4) * (LDIM / 64);

    // Q A-frags from global (sigmoid pre-applied in GEMM epilogue)
    s8v aQ[4];
    {
        const u16* qrow = ksig_bh + (size_t)(l0 + w * 16 + i15) * HD + quad * 8;
        #pragma unroll
        for (int kc = 0; kc < 4; ++kc) aQ[kc] = *(const s8v*)(qrow + kc * 32);
    }

    f32x4 accO[8];
    #pragma unroll
    for (int i = 0; i < 8; ++i) accO[i] = (f32x4)(0.f);
    float prs[4] = {0.f, 0.f, 0.f, 0.f};

    const float scale = 0.08838834764831845f;  // 1/sqrt(128)

    for (int m0 = 0; m0 < LDIM; m0 += 64) {
        // --- stage K tile via DMA: 64 rows x 16 segs, 4 insts/thread ---
        #pragma unroll
        for (int p = 0; p < 4; ++p) {
            int sb = (w * 4 + p) * 64;
            int s = sb + lane;
            int row = s >> 4;
            int seg = (s & 15) ^ (row & 15);
            const u16* g = ksig_bh + (size_t)(m0 + row) * HD + seg * 8;
            __builtin_amdgcn_global_load_lds(
                (const __attribute__((address_space(1))) unsigned int*)g,
                (__attribute__((address_space(3))) unsigned int*)&lds_ks[sb * 8], 16, 0, 0);
        }
        // --- stage V^T tile via DMA: 128 rows x 8 segs, 4 insts/thread ---
        #pragma unroll
        for (int p = 0; p < 4; ++p) {
            int sb = (w * 4 + p) * 64;
            int s = sb + lane;
            int row = s >> 3;
            int seg = (s & 7) ^ (row & 7);
            const u16* g = vt_bh + (size_t)row * LDIM + m0 + seg * 8;
            __builtin_amdgcn_global_load_lds(
                (const __attribute__((address_space(1))) unsigned int*)g,
                (__attribute__((address_space(3))) unsigned int*)&lds_vt[sb * 8], 16, 0, 0);
        }
        // --- adj mask words for this m-chunk (broadcast loads, hide under DMA) ---
        unsigned int mw0[4], mw1[4];
        #pragma unroll
        for (int r = 0; r < 4; ++r) {
            u64 wrd = abits[(size_t)r * (LDIM / 64) + (m0 >> 6)];
            mw0[r] = (unsigned int)wrd;
            mw1[r] = (unsigned int)(wrd >> 32);
        }
        __syncthreads();

        // --- S = sig(Q) sig(K)^T : 4 key-tiles x 4 k-steps ---
        f32x4 S[4];
        #pragma unroll
        for (int nt = 0; nt < 4; ++nt) {
            S[nt] = (f32x4)(0.f);
            #pragma unroll
            for (int kc = 0; kc < 4; ++kc) {
                int row = nt * 16 + i15;
                int slot = row * 16 + ((kc * 4 + quad) ^ (row & 15));
                s8v bK = *(const s8v*)&lds_ks[slot * 8];
                S[nt] = __builtin_amdgcn_mfma_f32_16x16x32_bf16(aQ[kc], bK, S[nt], 0, 0, 0);
            }
        }

        // --- mask via bit-test, rowsum, P -> LDS (per-wave, no barrier) ---
        #pragma unroll
        for (int nt = 0; nt < 4; ++nt) {
            int sh = (nt & 1) * 16 + i15;
            #pragma unroll
            for (int r = 0; r < 4; ++r) {
                unsigned int half = (nt < 2) ? mw0[r] : mw1[r];
                float p = ((half >> sh) & 1u) ? S[nt][r] * scale : 0.f;
                prs[r] += p;
                lds_ps[w][quad * 4 + r][nt * 16 + i15] = f2bf(p);
            }
        }

        // --- O += P . V ---
        {
            s8v aP[2];
            #pragma unroll
            for (int ks = 0; ks < 2; ++ks)
                aP[ks] = *(const s8v*)&lds_ps[w][i15][ks * 32 + quad * 8];
            #pragma unroll
            for (int ntd = 0; ntd < 8; ++ntd) {
                #pragma unroll
                for (int ks = 0; ks < 2; ++ks) {
                    int row = ntd * 16 + i15;
                    int slot = row * 8 + ((ks * 4 + quad) ^ (row & 7));
                    s8v bV = *(const s8v*)&lds_vt[slot * 8];
                    accO[ntd] = __builtin_amdgcn_mfma_f32_16x16x32_bf16(aP[ks], bV, accO[ntd], 0, 0, 0);
                }
            }
        }
        __syncthreads();
    }

    // --- epilogue: reduce rowsums across the 16 key-lanes, normalize, +res, relu ---
    float inv[4];
    #pragma unroll
    for (int r = 0; r < 4; ++r) {
        float s = prs[r];
        s += __shfl_xor(s, 1);
        s += __shfl_xor(s, 2);
        s += __shfl_xor(s, 4);
        s += __shfl_xor(s, 8);
        inv[r] = 1.0f / (s + 1e-6f);
    }
    #pragma unroll
    for (int ntd = 0; ntd < 8; ++ntd) {
        int dcol = h * HD + ntd * 16 + i15;
        #pragma unroll
        for (int r = 0; r < 4; ++r) {
            size_t idx = ((size_t)b * LDIM + l0 + w * 16 + quad * 4 + r) * CDIM + dcol;
            float v = accO[ntd][r] * inv[r] + bf2f(resb[idx]);
            out[idx] = fmaxf(v, 0.f);
        }
    }
}

// ---------------- launch ----------------
extern "C" void kernel_launch(void* const* d_in, const int* in_sizes, int n_in,
                              void* d_out, int out_size, void* d_ws, size_t ws_size,
                              hipStream_t stream) {
    (void)in_sizes; (void)n_in; (void)out_size; (void)ws_size;
    const float* x     = (const float*)d_in[0];
    const float* adj   = (const float*)d_in[1];
    const float* W_qkv = (const float*)d_in[2];
    const float* b_qkv = (const float*)d_in[3];
    const float* W_d   = (const float*)d_in[4];
    const float* b_d   = (const float*)d_in[5];
    float* out = (float*)d_out;

    char* ws = (char*)d_ws;
    size_t off = 0;
    float* deg  = (float*)(ws + off); off += 32768;                       // 8192 f32
    u64* adjb   = (u64*)(ws + off);   off += (size_t)MROWS * 8 * 8;       // 512 KB
    u16*   xg   = (u16*)(ws + off);   off += (size_t)MROWS * CDIM * 2;    // 16 MB
    u16*   Wt   = (u16*)(ws + off);   off += (size_t)N3 * CDIM * 2;       // 6 MB
    u16*   ksig = (u16*)(ws + off);   off += (size_t)MROWS * CDIM * 2;    // 16 MB
    u16*   resb = (u16*)(ws + off);   off += (size_t)MROWS * CDIM * 2;    // 16 MB
    u16*   vt   = (u16*)(ws + off);   off += (size_t)MROWS * CDIM * 2;    // 16 MB

    degree_kernel<<<MROWS, 64, 0, stream>>>(adj, deg, adjb);
    gate_kernel<<<MROWS, 256, 0, stream>>>(x, deg, W_d, b_d, xg);
    packW_kernel<<<dim3(CDIM / 64, N3 / 64), 256, 0, stream>>>(W_qkv, Wt);
    gemm_bf16_kernel<<<dim3(N3 / 256, MROWS / 256), 512, 0, stream>>>(xg, Wt, b_qkv, ksig, resb, vt);
    attn_kernel<<<LDIM / 64 * NH * BDIM, 256, 0, stream>>>(ksig, vt, resb, adjb, out);
}